// Round 6
// baseline (520.967 us; speedup 1.0000x reference)
//
#include <hip/hip_runtime.h>

constexpr int NX = 192, NY = 192, NZ = 192, NB = 2;
constexpr int ZPT  = 4;           // z outputs per thread
constexpr int TZ   = NZ / ZPT;    // 48
constexpr int BY   = 4;           // y rows per block
constexpr int XSEG = 4;           // x outputs per thread
constexpr int BLOCK_THREADS = TZ * BY;   // 192 = 3 waves
constexpr int PLANE = NY * NZ;
constexpr int NXB = NX / XSEG;    // 48
constexpr int NYB = NY / BY;      // 48
constexpr int NBLK = NYB * NXB * NB;     // 4608 blocks

// Fused load+fold of one x-plane: W[q][zz] = 3x3 (y,z)-window sums of the 5
// product quantities {t, p, t2, p2, tp} at the thread's 4 z outputs.
template<bool SAFE>
__device__ __forceinline__ void computeW(
    const float* __restrict__ pred, const float* __restrict__ label,
    int xx, const int rowoff[3], const float wy[3],
    int dm, int de, float wzm, float wze, float W[5][ZPT])
{
    const int xcl  = SAFE ? xx : min(max(xx, 0), NX - 1);
    const int xoff = xcl * PLANE;
    float S[5][6];
    #pragma unroll
    for (int r = 0; r < 3; ++r) {
        const int off = xoff + rowoff[r];
        const float4 t4 = *reinterpret_cast<const float4*>(label + off);
        const float4 p4 = *reinterpret_cast<const float4*>(pred + off);
        const float tm = label[off - dm], te = label[off + de];
        const float pm = pred[off - dm],  pe = pred[off + de];

        float tv[6] = {tm * wzm, t4.x, t4.y, t4.z, t4.w, te * wze};
        float pv[6] = {pm * wzm, p4.x, p4.y, p4.z, p4.w, pe * wze};
        if (!SAFE) {
            const float wx = ((unsigned)xx < (unsigned)NX) ? 1.f : 0.f;
            const float wr = wx * wy[r];          // w in {0,1} => exact masking
            #pragma unroll
            for (int j = 0; j < 6; ++j) { tv[j] *= wr; pv[j] *= wr; }
        }
        #pragma unroll
        for (int j = 0; j < 6; ++j) {
            if (r == 0) {
                S[0][j] = tv[j];
                S[1][j] = pv[j];
                S[2][j] = tv[j] * tv[j];
                S[3][j] = pv[j] * pv[j];
                S[4][j] = tv[j] * pv[j];
            } else {
                S[0][j] += tv[j];
                S[1][j] += pv[j];
                S[2][j] = fmaf(tv[j], tv[j], S[2][j]);
                S[3][j] = fmaf(pv[j], pv[j], S[3][j]);
                S[4][j] = fmaf(tv[j], pv[j], S[4][j]);
            }
        }
    }
    // 3-tap z-fold, 6 adds per quantity via pair reuse
    #pragma unroll
    for (int q = 0; q < 5; ++q) {
        const float m12 = S[q][1] + S[q][2];
        const float m34 = S[q][3] + S[q][4];
        W[q][0] = S[q][0] + m12;
        W[q][1] = m12 + S[q][3];
        W[q][2] = S[q][2] + m34;
        W[q][3] = m34 + S[q][5];
    }
}

__device__ __forceinline__ float epilogue4(const float P[5][ZPT], const float Wn[5][ZPT])
{
    constexpr float inv_vol = 1.0f / 27.0f;
    float acc = 0.f;
    #pragma unroll
    for (int zz = 0; zz < ZPT; ++zz) {
        const float st  = P[0][zz] + Wn[0][zz];
        const float sp  = P[1][zz] + Wn[1][zz];
        const float st2 = P[2][zz] + Wn[2][zz];
        const float sp2 = P[3][zz] + Wn[3][zz];
        const float stp = P[4][zz] + Wn[4][zz];
        const float tavg = st * inv_vol;
        const float pavg = sp * inv_vol;
        const float cross = fmaf(-pavg, st, stp);
        const float tvar  = fmaxf(fmaf(-tavg, st, st2), 0.f);
        const float pvar  = fmaxf(fmaf(-pavg, sp, sp2), 0.f);
        acc += cross * cross * __builtin_amdgcn_rcpf(fmaf(tvar, pvar, 1e-5f));
    }
    return acc;
}

template<bool SAFE>
__device__ __forceinline__ float march(const float* __restrict__ pred,
                                       const float* __restrict__ label,
                                       int xs0, const int rowoff[3], const float wy[3],
                                       int dm, int de, float wzm, float wze)
{
    float U[5][ZPT], V[5][ZPT], P[5][ZPT];

    computeW<SAFE>(pred, label, xs0 - 1, rowoff, wy, dm, de, wzm, wze, U);
    computeW<SAFE>(pred, label, xs0,     rowoff, wy, dm, de, wzm, wze, V);
    #pragma unroll
    for (int q = 0; q < 5; ++q)
        #pragma unroll
        for (int zz = 0; zz < ZPT; ++zz)
            P[q][zz] = U[q][zz] + V[q][zz];

    float acc = 0.f;
    #pragma unroll 1
    for (int k = 0; k < XSEG / 2; ++k) {
        // even: W(x+1) -> U ; out(x) = P + U ; P = V + U
        computeW<SAFE>(pred, label, xs0 + 1 + 2 * k, rowoff, wy, dm, de, wzm, wze, U);
        acc += epilogue4(P, U);
        #pragma unroll
        for (int q = 0; q < 5; ++q)
            #pragma unroll
            for (int zz = 0; zz < ZPT; ++zz)
                P[q][zz] = V[q][zz] + U[q][zz];

        // odd: W(x+2) -> V ; out(x+1) = P + V ; P = U + V
        computeW<SAFE>(pred, label, xs0 + 2 + 2 * k, rowoff, wy, dm, de, wzm, wze, V);
        acc += epilogue4(P, V);
        #pragma unroll
        for (int q = 0; q < 5; ++q)
            #pragma unroll
            for (int zz = 0; zz < ZPT; ++zz)
                P[q][zz] = U[q][zz] + V[q][zz];
    }
    return acc;
}

__global__ __launch_bounds__(BLOCK_THREADS, 6)   // cap VGPR at 85: TLP over ILP
void ncc_partial(const float* __restrict__ pred, const float* __restrict__ label,
                 float* __restrict__ partials)
{
    const int zc  = threadIdx.x;
    const int ty  = threadIdx.y;
    const int z0  = zc * ZPT;
    const int y   = blockIdx.x * BY + ty;
    const int xs0 = blockIdx.y * XSEG;
    const int b   = blockIdx.z;

    float wy[3];
    int   rowoff[3];
    #pragma unroll
    for (int r = 0; r < 3; ++r) {
        const int yy = y + r - 1;
        wy[r] = ((unsigned)yy < (unsigned)NY) ? 1.f : 0.f;
        const int yycl = min(max(yy, 0), NY - 1);
        rowoff[r] = b * (NX * PLANE) + yycl * NZ + z0;
    }
    const int   dm  = (zc == 0) ? 0 : 1;
    const int   de  = (zc == TZ - 1) ? 0 : ZPT;
    const float wzm = (zc == 0) ? 0.f : 1.f;
    const float wze = (zc == TZ - 1) ? 0.f : 1.f;

    // interior blocks: every x-plane and y-row touched is in range
    const bool safe = (blockIdx.x >= 1) && (blockIdx.x <= NYB - 2) &&
                      (blockIdx.y >= 1) && (blockIdx.y <= NXB - 2);

    const float acc = safe
        ? march<true >(pred, label, xs0, rowoff, wy, dm, de, wzm, wze)
        : march<false>(pred, label, xs0, rowoff, wy, dm, de, wzm, wze);

    // wave (64) reduction, then block sum
    float a = acc;
    #pragma unroll
    for (int o = 32; o > 0; o >>= 1)
        a += __shfl_down(a, o, 64);

    __shared__ float wsum[BLOCK_THREADS / 64];
    const int tid = threadIdx.x + threadIdx.y * TZ;
    if ((tid & 63) == 0) wsum[tid >> 6] = a;
    __syncthreads();
    if (tid == 0) {
        float s = 0.f;
        #pragma unroll
        for (int w = 0; w < BLOCK_THREADS / 64; ++w) s += wsum[w];
        partials[blockIdx.x + (int)gridDim.x * (blockIdx.y + (int)gridDim.y * blockIdx.z)] = s;
    }
}

__global__ __launch_bounds__(256)
void ncc_reduce(const float* __restrict__ partials, int n, float* __restrict__ out)
{
    __shared__ double sh[256];
    double s = 0.0;
    for (int i = threadIdx.x; i < n; i += 256) s += (double)partials[i];
    sh[threadIdx.x] = s;
    __syncthreads();
    for (int off = 128; off > 0; off >>= 1) {
        if ((int)threadIdx.x < off) sh[threadIdx.x] += sh[threadIdx.x + off];
        __syncthreads();
    }
    if (threadIdx.x == 0) {
        const double nvox = (double)NB * NX * NY * NZ;
        out[0] = (float)(-sh[0] / nvox);
    }
}

extern "C" void kernel_launch(void* const* d_in, const int* in_sizes, int n_in,
                              void* d_out, int out_size, void* d_ws, size_t ws_size,
                              hipStream_t stream) {
    const float* pred  = (const float*)d_in[0];
    const float* label = (const float*)d_in[1];
    float* out = (float*)d_out;
    float* partials = (float*)d_ws;

    dim3 block(TZ, BY, 1);                 // 48 x 4 = 192 threads
    dim3 grid(NYB, NXB, NB);               // 48 x 48 x 2 = 4608 blocks

    ncc_partial<<<grid, block, 0, stream>>>(pred, label, partials);
    ncc_reduce<<<1, 256, 0, stream>>>(partials, NBLK, out);
}

// Round 7
// 76.078 us; speedup vs baseline: 6.8478x; 6.8478x over previous
//
#include <hip/hip_runtime.h>

typedef float v2f __attribute__((ext_vector_type(2)));

constexpr int NX = 192, NY = 192, NZ = 192, NB = 2;
constexpr int ZPT  = 4;           // z outputs per thread
constexpr int TZ   = NZ / ZPT;    // 48
constexpr int BY   = 4;           // y rows per block
constexpr int XSEG = 8;           // x outputs per thread
constexpr int BLOCK_THREADS = TZ * BY;   // 192 = 3 waves
constexpr int PLANE = NY * NZ;
constexpr int NXB = NX / XSEG;    // 24
constexpr int NYB = NY / BY;      // 48
constexpr int NBLK = NYB * NXB * NB;     // 2304 blocks

// One x-plane: W[q] = 3x3 (y,z)-window sums of the 5 product quantities
// {t, p, t^2, p^2, t*p} at the thread's 4 z outputs, packed as 2x v2f.
// Packed (v_pk_*) f32 arithmetic: pairs over z.
template<bool SAFE>
__device__ __forceinline__ void computeW(
    const float* __restrict__ pred, const float* __restrict__ label,
    int xx, const int rowoff[3], const float wy[3],
    int dm, int de, float wzm, float wze, v2f W[5][2])
{
    const int xcl  = SAFE ? xx : min(max(xx, 0), NX - 1);
    const int xoff = xcl * PLANE;
    v2f S[5][3];
    #pragma unroll
    for (int r = 0; r < 3; ++r) {
        const int off = xoff + rowoff[r];
        const float4 t4 = *reinterpret_cast<const float4*>(label + off);
        const float4 p4 = *reinterpret_cast<const float4*>(pred + off);
        const float tm = label[off - dm] * wzm, te = label[off + de] * wze;
        const float pm = pred[off - dm]  * wzm, pe = pred[off + de]  * wze;

        v2f T[3]  = { v2f{tm, t4.x}, v2f{t4.y, t4.z}, v2f{t4.w, te} };
        v2f Pv[3] = { v2f{pm, p4.x}, v2f{p4.y, p4.z}, v2f{p4.w, pe} };
        if (!SAFE) {
            const float wx = ((unsigned)xx < (unsigned)NX) ? 1.f : 0.f;
            const float wr = wx * wy[r];          // w in {0,1} => exact masking
            #pragma unroll
            for (int j = 0; j < 3; ++j) { T[j] *= wr; Pv[j] *= wr; }
        }
        #pragma unroll
        for (int j = 0; j < 3; ++j) {
            if (r == 0) {
                S[0][j] = T[j];
                S[1][j] = Pv[j];
                S[2][j] = T[j] * T[j];
                S[3][j] = Pv[j] * Pv[j];
                S[4][j] = T[j] * Pv[j];
            } else {
                S[0][j] += T[j];
                S[1][j] += Pv[j];
                S[2][j] += T[j] * T[j];    // fp-contract -> v_pk_fma_f32
                S[3][j] += Pv[j] * Pv[j];
                S[4][j] += T[j] * Pv[j];
            }
        }
    }
    // 3-tap z-fold (scalar extracts are free: v2f components are registers)
    #pragma unroll
    for (int q = 0; q < 5; ++q) {
        const float s0 = S[q][0].x, s1 = S[q][0].y, s2 = S[q][1].x;
        const float s3 = S[q][1].y, s4 = S[q][2].x, s5 = S[q][2].y;
        const float m12 = s1 + s2;
        const float m34 = s3 + s4;
        W[q][0] = v2f{s0 + m12, m12 + s3};
        W[q][1] = v2f{s2 + m34, m34 + s5};
    }
}

__device__ __forceinline__ float epilogue4(const v2f P[5][2], const v2f Wn[5][2])
{
    constexpr float inv_vol = 1.0f / 27.0f;
    float acc = 0.f;
    #pragma unroll
    for (int h = 0; h < 2; ++h) {
        const v2f st  = P[0][h] + Wn[0][h];
        const v2f sp  = P[1][h] + Wn[1][h];
        const v2f st2 = P[2][h] + Wn[2][h];
        const v2f sp2 = P[3][h] + Wn[3][h];
        const v2f stp = P[4][h] + Wn[4][h];
        const v2f tavg = st * inv_vol;
        const v2f pavg = sp * inv_vol;
        const v2f cross = stp - pavg * st;     // pk_fma
        const v2f tvp   = st2 - tavg * st;     // pk_fma
        const v2f pvp   = sp2 - pavg * sp;     // pk_fma
        const v2f cc    = cross * cross;
        #pragma unroll
        for (int c = 0; c < 2; ++c) {
            const float tvar = fmaxf(tvp[c], 0.f);
            const float pvar = fmaxf(pvp[c], 0.f);
            acc += cc[c] * __builtin_amdgcn_rcpf(fmaf(tvar, pvar, 1e-5f));
        }
    }
    return acc;
}

template<bool SAFE>
__device__ __forceinline__ float march(const float* __restrict__ pred,
                                       const float* __restrict__ label,
                                       int xs0, const int rowoff[3], const float wy[3],
                                       int dm, int de, float wzm, float wze)
{
    v2f U[5][2], V[5][2], P[5][2];

    computeW<SAFE>(pred, label, xs0 - 1, rowoff, wy, dm, de, wzm, wze, U);
    computeW<SAFE>(pred, label, xs0,     rowoff, wy, dm, de, wzm, wze, V);
    #pragma unroll
    for (int q = 0; q < 5; ++q)
        #pragma unroll
        for (int h = 0; h < 2; ++h)
            P[q][h] = U[q][h] + V[q][h];

    float acc = 0.f;
    #pragma unroll 1
    for (int k = 0; k < XSEG / 2; ++k) {
        // even: W(x+1) -> U ; out(x) = P + U ; P = V + U
        computeW<SAFE>(pred, label, xs0 + 1 + 2 * k, rowoff, wy, dm, de, wzm, wze, U);
        acc += epilogue4(P, U);
        #pragma unroll
        for (int q = 0; q < 5; ++q)
            #pragma unroll
            for (int h = 0; h < 2; ++h)
                P[q][h] = V[q][h] + U[q][h];

        // odd: W(x+2) -> V ; out(x+1) = P + V ; P = U + V
        computeW<SAFE>(pred, label, xs0 + 2 + 2 * k, rowoff, wy, dm, de, wzm, wze, V);
        acc += epilogue4(P, V);
        #pragma unroll
        for (int q = 0; q < 5; ++q)
            #pragma unroll
            for (int h = 0; h < 2; ++h)
                P[q][h] = U[q][h] + V[q][h];
    }
    return acc;
}

__global__ __launch_bounds__(BLOCK_THREADS, 2)   // R3-proven stable point (VGPR~76)
void ncc_partial(const float* __restrict__ pred, const float* __restrict__ label,
                 float* __restrict__ partials)
{
    const int zc  = threadIdx.x;
    const int ty  = threadIdx.y;
    const int z0  = zc * ZPT;
    const int y   = blockIdx.x * BY + ty;
    const int xs0 = blockIdx.y * XSEG;
    const int b   = blockIdx.z;

    float wy[3];
    int   rowoff[3];
    #pragma unroll
    for (int r = 0; r < 3; ++r) {
        const int yy = y + r - 1;
        wy[r] = ((unsigned)yy < (unsigned)NY) ? 1.f : 0.f;
        const int yycl = min(max(yy, 0), NY - 1);
        rowoff[r] = b * (NX * PLANE) + yycl * NZ + z0;
    }
    const int   dm  = (zc == 0) ? 0 : 1;
    const int   de  = (zc == TZ - 1) ? 0 : ZPT;
    const float wzm = (zc == 0) ? 0.f : 1.f;
    const float wze = (zc == TZ - 1) ? 0.f : 1.f;

    const bool safe = (blockIdx.x >= 1) && (blockIdx.x <= NYB - 2) &&
                      (blockIdx.y >= 1) && (blockIdx.y <= NXB - 2);

    const float acc = safe
        ? march<true >(pred, label, xs0, rowoff, wy, dm, de, wzm, wze)
        : march<false>(pred, label, xs0, rowoff, wy, dm, de, wzm, wze);

    // wave (64) reduction, then block sum
    float a = acc;
    #pragma unroll
    for (int o = 32; o > 0; o >>= 1)
        a += __shfl_down(a, o, 64);

    __shared__ float wsum[BLOCK_THREADS / 64];
    const int tid = threadIdx.x + threadIdx.y * TZ;
    if ((tid & 63) == 0) wsum[tid >> 6] = a;
    __syncthreads();
    if (tid == 0) {
        float s = 0.f;
        #pragma unroll
        for (int w = 0; w < BLOCK_THREADS / 64; ++w) s += wsum[w];
        partials[blockIdx.x + (int)gridDim.x * (blockIdx.y + (int)gridDim.y * blockIdx.z)] = s;
    }
}

__global__ __launch_bounds__(256)
void ncc_reduce(const float* __restrict__ partials, int n, float* __restrict__ out)
{
    __shared__ double sh[256];
    double s = 0.0;
    for (int i = threadIdx.x; i < n; i += 256) s += (double)partials[i];
    sh[threadIdx.x] = s;
    __syncthreads();
    for (int off = 128; off > 0; off >>= 1) {
        if ((int)threadIdx.x < off) sh[threadIdx.x] += sh[threadIdx.x + off];
        __syncthreads();
    }
    if (threadIdx.x == 0) {
        const double nvox = (double)NB * NX * NY * NZ;
        out[0] = (float)(-sh[0] / nvox);
    }
}

extern "C" void kernel_launch(void* const* d_in, const int* in_sizes, int n_in,
                              void* d_out, int out_size, void* d_ws, size_t ws_size,
                              hipStream_t stream) {
    const float* pred  = (const float*)d_in[0];
    const float* label = (const float*)d_in[1];
    float* out = (float*)d_out;
    float* partials = (float*)d_ws;

    dim3 block(TZ, BY, 1);                 // 48 x 4 = 192 threads
    dim3 grid(NYB, NXB, NB);               // 48 x 24 x 2 = 2304 blocks

    ncc_partial<<<grid, block, 0, stream>>>(pred, label, partials);
    ncc_reduce<<<1, 256, 0, stream>>>(partials, NBLK, out);
}

// Round 8
// 49.944 us; speedup vs baseline: 10.4310x; 1.5233x over previous
//
#include <hip/hip_runtime.h>

typedef float v2f __attribute__((ext_vector_type(2)));

constexpr int NX = 192, NY = 192, NZ = 192, NB = 2;
constexpr int ZPT  = 4;            // z outputs per thread
constexpr int TZ   = NZ / ZPT;     // 48
constexpr int BY   = 4;            // y rows per block
constexpr int XSEG = 4;            // x outputs per thread
constexpr int BLOCK_THREADS = TZ * BY;   // 192 = 3 waves
constexpr int PLANE = NY * NZ;
constexpr int NXB = NX / XSEG;     // 48
constexpr int NYB = NY / BY;       // 48
constexpr int NBLK = NYB * NXB * NB;     // 4608 blocks
constexpr int TILE_F = 2 * 6 * NZ;       // 2304 floats per LDS buffer (2 tensors x 6 rows x 192 z)

// Fold one staged x-plane from LDS: W[q] = 3x3 (y,z)-window sums of
// {t, p, t^2, p^2, t*p} at the thread's 4 z outputs (as 2x v2f).
template<bool SAFE>
__device__ __forceinline__ void foldLDS(const float* __restrict__ buf,
    int ty, int z0, const float wy[3], int dm, int de, float wzm, float wze,
    float wx, v2f W[5][2])
{
    v2f S[5][3];
    #pragma unroll
    for (int r = 0; r < 3; ++r) {
        const float* Lt = buf + (ty + r) * NZ;          // label row
        const float* Lp = Lt + 6 * NZ;                  // pred row
        const float4 t4 = *reinterpret_cast<const float4*>(Lt + z0);
        const float4 p4 = *reinterpret_cast<const float4*>(Lp + z0);
        const float tm = Lt[z0 - dm] * wzm, te = Lt[z0 + de] * wze;
        const float pm = Lp[z0 - dm] * wzm, pe = Lp[z0 + de] * wze;
        v2f T[3]  = { v2f{tm, t4.x}, v2f{t4.y, t4.z}, v2f{t4.w, te} };
        v2f Pv[3] = { v2f{pm, p4.x}, v2f{p4.y, p4.z}, v2f{p4.w, pe} };
        if (!SAFE) {
            const float wr = wx * wy[r];                // w in {0,1} => exact
            #pragma unroll
            for (int q = 0; q < 3; ++q) { T[q] *= wr; Pv[q] *= wr; }
        }
        #pragma unroll
        for (int q = 0; q < 3; ++q) {
            if (r == 0) {
                S[0][q] = T[q];  S[1][q] = Pv[q];
                S[2][q] = T[q] * T[q];  S[3][q] = Pv[q] * Pv[q];  S[4][q] = T[q] * Pv[q];
            } else {
                S[0][q] += T[q];  S[1][q] += Pv[q];
                S[2][q] += T[q] * T[q];  S[3][q] += Pv[q] * Pv[q];  S[4][q] += T[q] * Pv[q];
            }
        }
    }
    #pragma unroll
    for (int q = 0; q < 5; ++q) {
        const float s0 = S[q][0].x, s1 = S[q][0].y, s2 = S[q][1].x;
        const float s3 = S[q][1].y, s4 = S[q][2].x, s5 = S[q][2].y;
        const float m12 = s1 + s2, m34 = s3 + s4;
        W[q][0] = v2f{s0 + m12, m12 + s3};
        W[q][1] = v2f{s2 + m34, m34 + s5};
    }
}

__device__ __forceinline__ float epilogue4(const v2f P[5][2], const v2f Wn[5][2])
{
    constexpr float inv_vol = 1.0f / 27.0f;
    float acc = 0.f;
    #pragma unroll
    for (int h = 0; h < 2; ++h) {
        const v2f st  = P[0][h] + Wn[0][h];
        const v2f sp  = P[1][h] + Wn[1][h];
        const v2f st2 = P[2][h] + Wn[2][h];
        const v2f sp2 = P[3][h] + Wn[3][h];
        const v2f stp = P[4][h] + Wn[4][h];
        const v2f tavg = st * inv_vol;
        const v2f pavg = sp * inv_vol;
        const v2f cross = stp - pavg * st;
        const v2f tvp   = st2 - tavg * st;
        const v2f pvp   = sp2 - pavg * sp;
        const v2f cc    = cross * cross;
        #pragma unroll
        for (int c = 0; c < 2; ++c) {
            const float tvar = fmaxf(tvp[c], 0.f);
            const float pvar = fmaxf(pvp[c], 0.f);
            acc += cc[c] * __builtin_amdgcn_rcpf(fmaf(tvar, pvar, 1e-5f));
        }
    }
    return acc;
}

// March over XSEG+2 = 6 x-planes with double-buffered LDS staging.
// Per step: issue next plane's 3 float4 global loads -> fold current plane
// from LDS -> ds_write the loaded plane -> barrier. (T14 issue-early/write-late)
template<bool SAFE>
__device__ __forceinline__ float march(
    const float* sb0, const float* sb1, const float* sb2,   // per-thread staging srcs (sans x)
    int lo0, int lo1, int lo2,                              // per-thread LDS float offsets
    float (*tile)[TILE_F],
    int ty, int z0, const float wy[3],
    int dm, int de, float wzm, float wze, int xs0)
{
    v2f U[5][2], V[5][2], P[5][2];
    float acc = 0.f;
    float4 G0, G1, G2;

#define XOFF(K) (SAFE ? (xs0 - 1 + (K)) * PLANE \
                      : min(max(xs0 - 1 + (K), 0), NX - 1) * PLANE)
#define WXK(K)  (SAFE ? 1.f : (((unsigned)(xs0 - 1 + (K)) < (unsigned)NX) ? 1.f : 0.f))
#define GLOAD(K) do { const int _xo = XOFF(K);                                  \
        G0 = *reinterpret_cast<const float4*>(sb0 + _xo);                       \
        G1 = *reinterpret_cast<const float4*>(sb1 + _xo);                       \
        G2 = *reinterpret_cast<const float4*>(sb2 + _xo); } while (0)
#define DSWR(K) do { float* _d = tile[(K) & 1];                                 \
        *reinterpret_cast<float4*>(_d + lo0) = G0;                              \
        *reinterpret_cast<float4*>(_d + lo1) = G1;                              \
        *reinterpret_cast<float4*>(_d + lo2) = G2; } while (0)
#define PSET(A, B) do { _Pragma("unroll")                                       \
        for (int q = 0; q < 5; ++q) { _Pragma("unroll")                         \
            for (int h = 0; h < 2; ++h) P[q][h] = A[q][h] + B[q][h]; } } while (0)

    // prologue: planes 0,1 staged; U=W(p0), V=W(p1), P=U+V
    GLOAD(0); DSWR(0); __syncthreads();
    GLOAD(1); foldLDS<SAFE>(tile[0], ty, z0, wy, dm, de, wzm, wze, WXK(0), U);
    DSWR(1);  __syncthreads();
    GLOAD(2); foldLDS<SAFE>(tile[1], ty, z0, wy, dm, de, wzm, wze, WXK(1), V);
    PSET(U, V);
    DSWR(2);  __syncthreads();

    // steady state: fold plane k, emit output xs0+k-2
    GLOAD(3); foldLDS<SAFE>(tile[0], ty, z0, wy, dm, de, wzm, wze, WXK(2), U);
    acc += epilogue4(P, U); PSET(V, U);
    DSWR(3);  __syncthreads();

    GLOAD(4); foldLDS<SAFE>(tile[1], ty, z0, wy, dm, de, wzm, wze, WXK(3), V);
    acc += epilogue4(P, V); PSET(U, V);
    DSWR(4);  __syncthreads();

    GLOAD(5); foldLDS<SAFE>(tile[0], ty, z0, wy, dm, de, wzm, wze, WXK(4), U);
    acc += epilogue4(P, U); PSET(V, U);
    DSWR(5);  __syncthreads();

    foldLDS<SAFE>(tile[1], ty, z0, wy, dm, de, wzm, wze, WXK(5), V);
    acc += epilogue4(P, V);

#undef XOFF
#undef WXK
#undef GLOAD
#undef DSWR
#undef PSET
    return acc;
}

__global__ __launch_bounds__(BLOCK_THREADS, 3)   // cap VGPR ~170: forbid R5 balloon
void ncc_partial(const float* __restrict__ pred, const float* __restrict__ label,
                 float* __restrict__ partials)
{
    __shared__ alignas(16) float tile[2][TILE_F];    // 18,432 B

    const int tx  = threadIdx.x;
    const int ty  = threadIdx.y;
    const int tid = tx + ty * TZ;
    const int z0  = tx * ZPT;
    const int y0  = blockIdx.x * BY;
    const int y   = y0 + ty;
    const int xs0 = blockIdx.y * XSEG;
    const int b   = blockIdx.z;
    const int bbase = b * NX * PLANE;

    // staging decomposition: flat float4-index j = r*192 + tid over
    // [tensor(2)][row(6)][z4(48)]; LDS float offset = 4*j.
    const float* sb[3];
    int lo[3];
    #pragma unroll
    for (int r = 0; r < 3; ++r) {
        const int j   = r * BLOCK_THREADS + tid;
        const int tt  = j / 288, rem = j - tt * 288;
        const int row = rem / 48, z4 = rem - row * 48;
        int grow = y0 - 1 + row;
        grow = min(max(grow, 0), NY - 1);
        sb[r] = (tt ? pred : label) + bbase + grow * NZ + z4 * 4;
        lo[r] = (tt * 6 + row) * NZ + z4 * 4;    // == 4*j
    }

    float wy[3];
    #pragma unroll
    for (int r = 0; r < 3; ++r) {
        const int yy = y + r - 1;
        wy[r] = ((unsigned)yy < (unsigned)NY) ? 1.f : 0.f;
    }
    const int   dm  = (tx == 0) ? 0 : 1;
    const int   de  = (tx == TZ - 1) ? 0 : ZPT;
    const float wzm = (tx == 0) ? 0.f : 1.f;
    const float wze = (tx == TZ - 1) ? 0.f : 1.f;

    const bool safe = (blockIdx.x >= 1) && (blockIdx.x <= NYB - 2) &&
                      (blockIdx.y >= 1) && (blockIdx.y <= NXB - 2);

    const float acc = safe
        ? march<true >(sb[0], sb[1], sb[2], lo[0], lo[1], lo[2], tile,
                       ty, z0, wy, dm, de, wzm, wze, xs0)
        : march<false>(sb[0], sb[1], sb[2], lo[0], lo[1], lo[2], tile,
                       ty, z0, wy, dm, de, wzm, wze, xs0);

    // wave (64) reduction, then block sum
    float a = acc;
    #pragma unroll
    for (int o = 32; o > 0; o >>= 1)
        a += __shfl_down(a, o, 64);

    __shared__ float wsum[BLOCK_THREADS / 64];
    if ((tid & 63) == 0) wsum[tid >> 6] = a;
    __syncthreads();
    if (tid == 0) {
        float s = 0.f;
        #pragma unroll
        for (int w = 0; w < BLOCK_THREADS / 64; ++w) s += wsum[w];
        partials[blockIdx.x + (int)gridDim.x * (blockIdx.y + (int)gridDim.y * blockIdx.z)] = s;
    }
}

__global__ __launch_bounds__(256)
void ncc_reduce(const float* __restrict__ partials, int n, float* __restrict__ out)
{
    __shared__ double sh[256];
    double s = 0.0;
    for (int i = threadIdx.x; i < n; i += 256) s += (double)partials[i];
    sh[threadIdx.x] = s;
    __syncthreads();
    for (int off = 128; off > 0; off >>= 1) {
        if ((int)threadIdx.x < off) sh[threadIdx.x] += sh[threadIdx.x + off];
        __syncthreads();
    }
    if (threadIdx.x == 0) {
        const double nvox = (double)NB * NX * NY * NZ;
        out[0] = (float)(-sh[0] / nvox);
    }
}

extern "C" void kernel_launch(void* const* d_in, const int* in_sizes, int n_in,
                              void* d_out, int out_size, void* d_ws, size_t ws_size,
                              hipStream_t stream) {
    const float* pred  = (const float*)d_in[0];
    const float* label = (const float*)d_in[1];
    float* out = (float*)d_out;
    float* partials = (float*)d_ws;

    dim3 block(TZ, BY, 1);                 // 48 x 4 = 192 threads
    dim3 grid(NYB, NXB, NB);               // 48 x 48 x 2 = 4608 blocks

    ncc_partial<<<grid, block, 0, stream>>>(pred, label, partials);
    ncc_reduce<<<1, 256, 0, stream>>>(partials, NBLK, out);
}